// Round 11
// baseline (66.018 us; speedup 1.0000x reference)
//
#include <hip/hip_runtime.h>
#include <hip/hip_fp16.h>

// Composite loss: 0.16*MSE + 0.84*(1-SSIM), 16x3x512x512 f32, win=11 sigma=1.5
// R11: OH=8 strips, TWO-PASS phase B over half the row-pairs each ->
//   LDS = 5 planes x 2 row-pairs x 512 half2 (+pad) = 20512 B (5 blocks/CU)
//   phase B mapping back to conflict-free (128 threads x 16B contiguous/row)
//   phase A unchanged: stream 18 rows, pk-fp16 vertical conv, 2x2 repack
//   reduce: per-block partial -> d_ws; 1-block float4 tree reduce.

#define OH 8

struct __align__(8) H2x2 { __half2 a, b; };

__global__ __launch_bounds__(256, 5) void ssim_fused(
    const float* __restrict__ pred, const float* __restrict__ targ,
    float2* __restrict__ part)
{
    __shared__ __half2 sPh2[5 * 2 * 512 + 8];   // 20512 B: [plane][rpl][col]

    // Normalized 11-tap Gaussian (sigma=1.5)
    const float wv[11] = {
        0.00102838f, 0.00759876f, 0.03600078f, 0.10936070f, 0.21300554f,
        0.26601173f,
        0.21300554f, 0.10936070f, 0.03600078f, 0.00759876f, 0.00102838f };
    __half2 wh[11];
    #pragma unroll
    for (int k = 0; k < 11; ++k) wh[k] = __float2half2_rn(wv[k]);

    const int tid = threadIdx.x;
    // XCD-aware bijective swizzle: 3072 blocks = 8 XCDs * 384
    const int bid = ((int)blockIdx.x & 7) * 384 + ((int)blockIdx.x >> 3);
    const int img = bid >> 6;             // 48 planes
    const int oy0 = (bid & 63) * OH;      // 64 row-strips
    const float* __restrict__ P = pred + (size_t)img * (512 * 512);
    const float* __restrict__ T = targ + (size_t)img * (512 * 512);

    // ---------------- phase A: stream 18 rows, pk-fp16 vertical conv --------
    const int c0 = tid * 2;

    __half2 va[5][OH];               // packed col-pair accumulators
    #pragma unroll
    for (int p = 0; p < 5; ++p)
        #pragma unroll
        for (int j = 0; j < OH; ++j) va[p][j] = __float2half2_rn(0.0f);

    float mse_acc = 0.f;

    #pragma unroll
    for (int i = 0; i < OH + 10; ++i) {
        int gy = oy0 + i; if (gy > 511) gy = 511;   // clamped rows feed only masked outputs
        const float2 xv = *reinterpret_cast<const float2*>(P + gy * 512 + c0);
        const float2 yv = *reinterpret_cast<const float2*>(T + gy * 512 + c0);
        const float x0 = __builtin_amdgcn_fmed3f(xv.x, 0.f, 1.f);
        const float x1 = __builtin_amdgcn_fmed3f(xv.y, 0.f, 1.f);
        const float y0 = __builtin_amdgcn_fmed3f(yv.x, 0.f, 1.f);
        const float y1 = __builtin_amdgcn_fmed3f(yv.y, 0.f, 1.f);
        if (i < OH) {   // this block's disjoint MSE rows (fp32)
            const float d0 = x0 - y0, d1 = x1 - y1;
            mse_acc = fmaf(d0, d0, mse_acc);
            mse_acc = fmaf(d1, d1, mse_acc);
        }
        const __half2 hx = __float22half2_rn(make_float2(x0, x1));
        const __half2 hy = __float22half2_rn(make_float2(y0, y1));
        const __half2 pr[5] = { hx, hy, __hmul2(hx, hx), __hmul2(hy, hy),
                                __hmul2(hx, hy) };
        #pragma unroll
        for (int j = 0; j < OH; ++j) {
            const int k = i - j;
            if (k >= 0 && k <= 10) {
                #pragma unroll
                for (int p = 0; p < 5; ++p)
                    va[p][j] = __hfma2(wh[k], pr[p], va[p][j]);
            }
        }
    }

    // ------------- two passes: store 2 row-pairs, conv+map them -------------
    float ssim_acc = 0.f;
    const float C1 = 0.0001f, C2 = 0.0009f;

    const int rpl = tid >> 7;           // local row-pair 0..1
    const int oc0 = (tid & 127) * 4;    // output cols oc0..oc0+3
    // groups with oc0>=504 are fully masked; clamp their reads in-row
    const int rc0 = (oc0 >= 504) ? 496 : oc0;

    #pragma unroll
    for (int half = 0; half < 2; ++half) {
        if (half) __syncthreads();      // pass-0 reads done before overwrite

        // store row-pairs jp = 2*half+jpl as ONE 8B write each
        #pragma unroll
        for (int p = 0; p < 5; ++p)
            #pragma unroll
            for (int jpl = 0; jpl < 2; ++jpl) {
                const int jp = 2 * half + jpl;
                const __half2 a = va[p][2 * jp], b = va[p][2 * jp + 1];
                H2x2 st;
                st.a = __halves2half2(__low2half(a),  __low2half(b));
                st.b = __halves2half2(__high2half(a), __high2half(b));
                *reinterpret_cast<H2x2*>(&sPh2[(p * 2 + jpl) * 512 + c0]) = st;
            }

        __syncthreads();

        // conflict-free horizontal conv: lane reads contiguous 16B chunks
        __half2 hc[5][4];
        union U4 { float4 f4; __half2 h2[4]; };
        union U2 { float2 f2; __half2 h2[2]; };
        #pragma unroll
        for (int p = 0; p < 5; ++p) {
            const __half2* base = &sPh2[(p * 2 + rpl) * 512 + rc0];
            __half2 win[14];
            U4 u0, u1, u2; U2 u3;
            u0.f4 = *reinterpret_cast<const float4*>(base);
            u1.f4 = *reinterpret_cast<const float4*>(base + 4);
            u2.f4 = *reinterpret_cast<const float4*>(base + 8);
            u3.f2 = *reinterpret_cast<const float2*>(base + 12);
            #pragma unroll
            for (int q = 0; q < 4; ++q) {
                win[q]     = u0.h2[q];
                win[q + 4] = u1.h2[q];
                win[q + 8] = u2.h2[q];
            }
            win[12] = u3.h2[0]; win[13] = u3.h2[1];
            #pragma unroll
            for (int cc = 0; cc < 4; ++cc) {
                __half2 s = __float2half2_rn(0.0f);
                #pragma unroll
                for (int t = 0; t < 11; ++t)
                    s = __hfma2(wh[t], win[cc + t], s);
                hc[p][cc] = s;
            }
        }

        // SSIM map (fp32), rows 2*rp, 2*rp+1 packed in lo/hi
        const int rp  = 2 * half + rpl;
        const int ylo = oy0 + 2 * rp;
        const bool vlo = ylo < 502, vhi = (ylo + 1) < 502;
        #pragma unroll
        for (int cc = 0; cc < 4; ++cc) {
            if (oc0 + cc < 502) {          // oc0-based: shifted groups masked
                #pragma unroll
                for (int h = 0; h < 2; ++h) {
                    if (h ? vhi : vlo) {
                        const float mu1 = h ? __high2float(hc[0][cc]) : __low2float(hc[0][cc]);
                        const float mu2 = h ? __high2float(hc[1][cc]) : __low2float(hc[1][cc]);
                        const float exx = h ? __high2float(hc[2][cc]) : __low2float(hc[2][cc]);
                        const float eyy = h ? __high2float(hc[3][cc]) : __low2float(hc[3][cc]);
                        const float exy = h ? __high2float(hc[4][cc]) : __low2float(hc[4][cc]);
                        const float m11 = mu1 * mu1, m22 = mu2 * mu2, m12 = mu1 * mu2;
                        const float s1  = exx - m11;
                        const float s2  = eyy - m22;
                        const float s12 = exy - m12;
                        const float num = (2.f * m12 + C1) * (2.f * s12 + C2);
                        const float den = (m11 + m22 + C1) * (s1 + s2 + C2);
                        ssim_acc += num * __builtin_amdgcn_rcpf(den);
                    }
                }
            }
        }
    }

    // -------- block reduction: wave shfl -> LDS -> ONE store per block ------
    float vx = mse_acc, vy = ssim_acc;
    #pragma unroll
    for (int off = 32; off > 0; off >>= 1) {
        vx += __shfl_down(vx, off);
        vy += __shfl_down(vy, off);
    }
    __syncthreads();                     // phase-B LDS reads done; reuse sPh2
    float* redf = reinterpret_cast<float*>(sPh2);
    const int wave = tid >> 6;
    if ((tid & 63) == 0) { redf[wave * 2] = vx; redf[wave * 2 + 1] = vy; }
    __syncthreads();
    if (tid == 0) {
        part[bid] = make_float2(redf[0] + redf[2] + redf[4] + redf[6],
                                redf[1] + redf[3] + redf[5] + redf[7]);
    }
}

__global__ __launch_bounds__(256) void ssim_reduce(
    const float2* __restrict__ part, float* __restrict__ out)
{
    __shared__ float red[8];
    const int tid = threadIdx.x;
    const float4* p4 = reinterpret_cast<const float4*>(part);  // 1536 float4
    float ms = 0.f, ss = 0.f;
    #pragma unroll
    for (int k = 0; k < 6; ++k) {
        const float4 v = p4[tid + k * 256];
        ms += v.x + v.z; ss += v.y + v.w;
    }
    #pragma unroll
    for (int off = 32; off > 0; off >>= 1) {
        ms += __shfl_down(ms, off);
        ss += __shfl_down(ss, off);
    }
    const int wave = tid >> 6;
    if ((tid & 63) == 0) { red[wave * 2] = ms; red[wave * 2 + 1] = ss; }
    __syncthreads();
    if (tid == 0) {
        const float msum = red[0] + red[2] + red[4] + red[6];
        const float ssum = red[1] + red[3] + red[5] + red[7];
        // N_mse = 16*3*512*512 = 12582912 ; N_ssim = 16*3*502*502 = 12096192
        const float mse  = msum * (1.0f / 12582912.0f);
        const float ssim = ssum * (1.0f / 12096192.0f);
        out[0] = 0.16f * mse + 0.84f * (1.0f - ssim);
    }
}

extern "C" void kernel_launch(void* const* d_in, const int* in_sizes, int n_in,
                              void* d_out, int out_size, void* d_ws, size_t ws_size,
                              hipStream_t stream)
{
    const float* pred = (const float*)d_in[0];
    const float* targ = (const float*)d_in[1];
    float2* part = (float2*)d_ws;      // 3072 * 8 B, fully rewritten each launch

    // 48 planes * 64 row-strips = 3072 blocks
    ssim_fused<<<3072, 256, 0, stream>>>(pred, targ, part);
    ssim_reduce<<<1, 256, 0, stream>>>(part, (float*)d_out);
}

// Round 12
// 44.043 us; speedup vs baseline: 1.4989x; 1.4989x over previous
//
#include <hip/hip_runtime.h>
#include <hip/hip_fp16.h>

// Composite loss: 0.16*MSE + 0.84*(1-SSIM), 16x3x512x512 f32, win=11 sigma=1.5
// R12 = R10 structure with conflict-free phase B + bigger VGPR budget:
//   phase A: per-thread 2 cols, stream 18 rows, pk-fp16 vertical conv
//            (5 planes x 8 rows), 2x2 repack -> row-pair planes in LDS (40960B)
//   phase B: 128 threads x contiguous 16B per plane-row (thread: 4 cols x
//            2 row-pairs) -- R9's conflict-free pattern; +8 half2 pad for edges
//   reduce:  per-block partial -> d_ws; 1-block float4 tree reduce.

#define OH 8

struct __align__(8) H2x2 { __half2 a, b; };

__global__ __launch_bounds__(256, 3) void ssim_fused(
    const float* __restrict__ pred, const float* __restrict__ targ,
    float2* __restrict__ part)
{
    __shared__ __half2 sPh2[5 * 4 * 512 + 8];   // 40992 B: [plane][rowpair][col]

    // Normalized 11-tap Gaussian (sigma=1.5)
    const float wv[11] = {
        0.00102838f, 0.00759876f, 0.03600078f, 0.10936070f, 0.21300554f,
        0.26601173f,
        0.21300554f, 0.10936070f, 0.03600078f, 0.00759876f, 0.00102838f };
    __half2 wh[11];
    #pragma unroll
    for (int k = 0; k < 11; ++k) wh[k] = __float2half2_rn(wv[k]);

    const int tid = threadIdx.x;
    // XCD-aware bijective swizzle: 3072 blocks = 8 XCDs * 384
    const int bid = ((int)blockIdx.x & 7) * 384 + ((int)blockIdx.x >> 3);
    const int img = bid >> 6;             // 48 planes
    const int oy0 = (bid & 63) * OH;      // 64 row-strips
    const float* __restrict__ P = pred + (size_t)img * (512 * 512);
    const float* __restrict__ T = targ + (size_t)img * (512 * 512);

    // ---------------- phase A: stream 18 rows, pk-fp16 vertical conv --------
    const int c0 = tid * 2;

    __half2 va[5][OH];               // packed col-pair accumulators
    #pragma unroll
    for (int p = 0; p < 5; ++p)
        #pragma unroll
        for (int j = 0; j < OH; ++j) va[p][j] = __float2half2_rn(0.0f);

    float mse_acc = 0.f;

    #pragma unroll
    for (int i = 0; i < OH + 10; ++i) {
        int gy = oy0 + i; if (gy > 511) gy = 511;   // clamped rows feed only masked outputs
        const float2 xv = *reinterpret_cast<const float2*>(P + gy * 512 + c0);
        const float2 yv = *reinterpret_cast<const float2*>(T + gy * 512 + c0);
        const float x0 = __builtin_amdgcn_fmed3f(xv.x, 0.f, 1.f);
        const float x1 = __builtin_amdgcn_fmed3f(xv.y, 0.f, 1.f);
        const float y0 = __builtin_amdgcn_fmed3f(yv.x, 0.f, 1.f);
        const float y1 = __builtin_amdgcn_fmed3f(yv.y, 0.f, 1.f);
        if (i < OH) {   // this block's disjoint MSE rows (fp32)
            const float d0 = x0 - y0, d1 = x1 - y1;
            mse_acc = fmaf(d0, d0, mse_acc);
            mse_acc = fmaf(d1, d1, mse_acc);
        }
        const __half2 hx = __float22half2_rn(make_float2(x0, x1));
        const __half2 hy = __float22half2_rn(make_float2(y0, y1));
        const __half2 pr[5] = { hx, hy, __hmul2(hx, hx), __hmul2(hy, hy),
                                __hmul2(hx, hy) };
        #pragma unroll
        for (int j = 0; j < OH; ++j) {
            const int k = i - j;
            if (k >= 0 && k <= 10) {
                #pragma unroll
                for (int p = 0; p < 5; ++p)
                    va[p][j] = __hfma2(wh[k], pr[p], va[p][j]);
            }
        }
    }

    // repack 2x2 and store both half2 as ONE 8B write:
    // sPh2[(p*4+jp)*512 + c0] = (lo(a),lo(b)) ; +1 = (hi(a),hi(b))
    #pragma unroll
    for (int p = 0; p < 5; ++p)
        #pragma unroll
        for (int jp = 0; jp < 4; ++jp) {
            const __half2 a = va[p][2 * jp], b = va[p][2 * jp + 1];
            H2x2 st;
            st.a = __halves2half2(__low2half(a),  __low2half(b));
            st.b = __halves2half2(__high2half(a), __high2half(b));
            *reinterpret_cast<H2x2*>(&sPh2[(p * 4 + jp) * 512 + c0]) = st;
        }

    __syncthreads();

    // ------- phase B: conflict-free 128-thread rows, 2 row-pairs/thread -----
    const int rpl = tid >> 7;           // 0..1 -> row-pairs rpl, rpl+2
    const int oc0 = (tid & 127) * 4;    // output cols oc0..oc0+3
    // oc0 in {504,508}: all outputs masked; clamp reads in-row
    const int rc0 = (oc0 >= 504) ? 496 : oc0;

    float ssim_acc = 0.f;
    const float C1 = 0.0001f, C2 = 0.0009f;
    union U4 { float4 f4; __half2 h2[4]; };
    union U2 { float2 f2; __half2 h2[2]; };

    #pragma unroll
    for (int rr = 0; rr < 2; ++rr) {
        const int rp = rpl + 2 * rr;    // 0,2 or 1,3

        __half2 hc[5][4];
        #pragma unroll
        for (int p = 0; p < 5; ++p) {
            const __half2* base = &sPh2[(p * 4 + rp) * 512 + rc0];
            __half2 win[14];
            U4 u0, u1, u2; U2 u3;
            u0.f4 = *reinterpret_cast<const float4*>(base);
            u1.f4 = *reinterpret_cast<const float4*>(base + 4);
            u2.f4 = *reinterpret_cast<const float4*>(base + 8);
            u3.f2 = *reinterpret_cast<const float2*>(base + 12);
            #pragma unroll
            for (int q = 0; q < 4; ++q) {
                win[q]     = u0.h2[q];
                win[q + 4] = u1.h2[q];
                win[q + 8] = u2.h2[q];
            }
            win[12] = u3.h2[0]; win[13] = u3.h2[1];
            #pragma unroll
            for (int cc = 0; cc < 4; ++cc) {
                __half2 s = __float2half2_rn(0.0f);
                #pragma unroll
                for (int t = 0; t < 11; ++t)
                    s = __hfma2(wh[t], win[cc + t], s);
                hc[p][cc] = s;
            }
        }

        // SSIM map (fp32); rows 2*rp (lo), 2*rp+1 (hi)
        const int ylo = oy0 + 2 * rp;
        const bool vlo = ylo < 502, vhi = (ylo + 1) < 502;
        #pragma unroll
        for (int cc = 0; cc < 4; ++cc) {
            if (oc0 + cc < 502) {          // oc0-based: shifted groups masked
                #pragma unroll
                for (int h = 0; h < 2; ++h) {
                    if (h ? vhi : vlo) {
                        const float mu1 = h ? __high2float(hc[0][cc]) : __low2float(hc[0][cc]);
                        const float mu2 = h ? __high2float(hc[1][cc]) : __low2float(hc[1][cc]);
                        const float exx = h ? __high2float(hc[2][cc]) : __low2float(hc[2][cc]);
                        const float eyy = h ? __high2float(hc[3][cc]) : __low2float(hc[3][cc]);
                        const float exy = h ? __high2float(hc[4][cc]) : __low2float(hc[4][cc]);
                        const float m11 = mu1 * mu1, m22 = mu2 * mu2, m12 = mu1 * mu2;
                        const float s1  = exx - m11;
                        const float s2  = eyy - m22;
                        const float s12 = exy - m12;
                        const float num = (2.f * m12 + C1) * (2.f * s12 + C2);
                        const float den = (m11 + m22 + C1) * (s1 + s2 + C2);
                        ssim_acc += num * __builtin_amdgcn_rcpf(den);
                    }
                }
            }
        }
    }

    // -------- block reduction: wave shfl -> LDS -> ONE store per block ------
    float vx = mse_acc, vy = ssim_acc;
    #pragma unroll
    for (int off = 32; off > 0; off >>= 1) {
        vx += __shfl_down(vx, off);
        vy += __shfl_down(vy, off);
    }
    __syncthreads();                     // phase-B LDS reads done; reuse sPh2
    float* redf = reinterpret_cast<float*>(sPh2);
    const int wave = tid >> 6;
    if ((tid & 63) == 0) { redf[wave * 2] = vx; redf[wave * 2 + 1] = vy; }
    __syncthreads();
    if (tid == 0) {
        part[bid] = make_float2(redf[0] + redf[2] + redf[4] + redf[6],
                                redf[1] + redf[3] + redf[5] + redf[7]);
    }
}

__global__ __launch_bounds__(256) void ssim_reduce(
    const float2* __restrict__ part, float* __restrict__ out)
{
    __shared__ float red[8];
    const int tid = threadIdx.x;
    const float4* p4 = reinterpret_cast<const float4*>(part);  // 1536 float4
    float ms = 0.f, ss = 0.f;
    #pragma unroll
    for (int k = 0; k < 6; ++k) {
        const float4 v = p4[tid + k * 256];
        ms += v.x + v.z; ss += v.y + v.w;
    }
    #pragma unroll
    for (int off = 32; off > 0; off >>= 1) {
        ms += __shfl_down(ms, off);
        ss += __shfl_down(ss, off);
    }
    const int wave = tid >> 6;
    if ((tid & 63) == 0) { red[wave * 2] = ms; red[wave * 2 + 1] = ss; }
    __syncthreads();
    if (tid == 0) {
        const float msum = red[0] + red[2] + red[4] + red[6];
        const float ssum = red[1] + red[3] + red[5] + red[7];
        // N_mse = 16*3*512*512 = 12582912 ; N_ssim = 16*3*502*502 = 12096192
        const float mse  = msum * (1.0f / 12582912.0f);
        const float ssim = ssum * (1.0f / 12096192.0f);
        out[0] = 0.16f * mse + 0.84f * (1.0f - ssim);
    }
}

extern "C" void kernel_launch(void* const* d_in, const int* in_sizes, int n_in,
                              void* d_out, int out_size, void* d_ws, size_t ws_size,
                              hipStream_t stream)
{
    const float* pred = (const float*)d_in[0];
    const float* targ = (const float*)d_in[1];
    float2* part = (float2*)d_ws;      // 3072 * 8 B, fully rewritten each launch

    // 48 planes * 64 row-strips = 3072 blocks
    ssim_fused<<<3072, 256, 0, stream>>>(pred, targ, part);
    ssim_reduce<<<1, 256, 0, stream>>>(part, (float*)d_out);
}

// Round 13
// 43.094 us; speedup vs baseline: 1.5319x; 1.0220x over previous
//
#include <hip/hip_runtime.h>
#include <hip/hip_fp16.h>

// Composite loss: 0.16*MSE + 0.84*(1-SSIM), 16x3x512x512 f32, win=11 sigma=1.5
// R13 = R11 two-pass structure + launch_bounds(256,4) (128-VGPR cap).
// R11's 85MB scratch spill was the (256,5)=102-reg cap colliding with ~110
// live at the plane-store point; only 20 va regs stay live across pass 0.
//   phase A: stream 18 rows, pk-fp16 vertical conv (5 planes x 8 rows)
//   two passes: store 2 row-pairs (20512B LDS), conflict-free horizontal conv
//               + fp32 SSIM map, barrier, repeat for the other 2 row-pairs
//   reduce: per-block partial -> d_ws; 1-block float4 tree reduce.

#define OH 8

struct __align__(8) H2x2 { __half2 a, b; };

__global__ __launch_bounds__(256, 4) void ssim_fused(
    const float* __restrict__ pred, const float* __restrict__ targ,
    float2* __restrict__ part)
{
    __shared__ __half2 sPh2[5 * 2 * 512 + 8];   // 20512 B: [plane][rpl][col]

    // Normalized 11-tap Gaussian (sigma=1.5)
    const float wv[11] = {
        0.00102838f, 0.00759876f, 0.03600078f, 0.10936070f, 0.21300554f,
        0.26601173f,
        0.21300554f, 0.10936070f, 0.03600078f, 0.00759876f, 0.00102838f };
    __half2 wh[11];
    #pragma unroll
    for (int k = 0; k < 11; ++k) wh[k] = __float2half2_rn(wv[k]);

    const int tid = threadIdx.x;
    // XCD-aware bijective swizzle: 3072 blocks = 8 XCDs * 384
    const int bid = ((int)blockIdx.x & 7) * 384 + ((int)blockIdx.x >> 3);
    const int img = bid >> 6;             // 48 planes
    const int oy0 = (bid & 63) * OH;      // 64 row-strips
    const float* __restrict__ P = pred + (size_t)img * (512 * 512);
    const float* __restrict__ T = targ + (size_t)img * (512 * 512);

    // ---------------- phase A: stream 18 rows, pk-fp16 vertical conv --------
    const int c0 = tid * 2;

    __half2 va[5][OH];               // packed col-pair accumulators
    #pragma unroll
    for (int p = 0; p < 5; ++p)
        #pragma unroll
        for (int j = 0; j < OH; ++j) va[p][j] = __float2half2_rn(0.0f);

    float mse_acc = 0.f;

    #pragma unroll
    for (int i = 0; i < OH + 10; ++i) {
        int gy = oy0 + i; if (gy > 511) gy = 511;   // clamped rows feed only masked outputs
        const float2 xv = *reinterpret_cast<const float2*>(P + gy * 512 + c0);
        const float2 yv = *reinterpret_cast<const float2*>(T + gy * 512 + c0);
        const float x0 = __builtin_amdgcn_fmed3f(xv.x, 0.f, 1.f);
        const float x1 = __builtin_amdgcn_fmed3f(xv.y, 0.f, 1.f);
        const float y0 = __builtin_amdgcn_fmed3f(yv.x, 0.f, 1.f);
        const float y1 = __builtin_amdgcn_fmed3f(yv.y, 0.f, 1.f);
        if (i < OH) {   // this block's disjoint MSE rows (fp32)
            const float d0 = x0 - y0, d1 = x1 - y1;
            mse_acc = fmaf(d0, d0, mse_acc);
            mse_acc = fmaf(d1, d1, mse_acc);
        }
        const __half2 hx = __float22half2_rn(make_float2(x0, x1));
        const __half2 hy = __float22half2_rn(make_float2(y0, y1));
        const __half2 pr[5] = { hx, hy, __hmul2(hx, hx), __hmul2(hy, hy),
                                __hmul2(hx, hy) };
        #pragma unroll
        for (int j = 0; j < OH; ++j) {
            const int k = i - j;
            if (k >= 0 && k <= 10) {
                #pragma unroll
                for (int p = 0; p < 5; ++p)
                    va[p][j] = __hfma2(wh[k], pr[p], va[p][j]);
            }
        }
    }

    // ------------- two passes: store 2 row-pairs, conv+map them -------------
    float ssim_acc = 0.f;
    const float C1 = 0.0001f, C2 = 0.0009f;

    const int rpl = tid >> 7;           // local row-pair 0..1
    const int oc0 = (tid & 127) * 4;    // output cols oc0..oc0+3
    // groups with oc0>=504 are fully masked; clamp their reads in-row
    const int rc0 = (oc0 >= 504) ? 496 : oc0;

    #pragma unroll
    for (int half = 0; half < 2; ++half) {
        if (half) __syncthreads();      // pass-0 reads done before overwrite

        // store row-pairs jp = 2*half+jpl as ONE 8B write each
        #pragma unroll
        for (int p = 0; p < 5; ++p)
            #pragma unroll
            for (int jpl = 0; jpl < 2; ++jpl) {
                const int jp = 2 * half + jpl;
                const __half2 a = va[p][2 * jp], b = va[p][2 * jp + 1];
                H2x2 st;
                st.a = __halves2half2(__low2half(a),  __low2half(b));
                st.b = __halves2half2(__high2half(a), __high2half(b));
                *reinterpret_cast<H2x2*>(&sPh2[(p * 2 + jpl) * 512 + c0]) = st;
            }

        __syncthreads();

        // conflict-free horizontal conv: lane reads contiguous 16B chunks
        __half2 hc[5][4];
        union U4 { float4 f4; __half2 h2[4]; };
        union U2 { float2 f2; __half2 h2[2]; };
        #pragma unroll
        for (int p = 0; p < 5; ++p) {
            const __half2* base = &sPh2[(p * 2 + rpl) * 512 + rc0];
            __half2 win[14];
            U4 u0, u1, u2; U2 u3;
            u0.f4 = *reinterpret_cast<const float4*>(base);
            u1.f4 = *reinterpret_cast<const float4*>(base + 4);
            u2.f4 = *reinterpret_cast<const float4*>(base + 8);
            u3.f2 = *reinterpret_cast<const float2*>(base + 12);
            #pragma unroll
            for (int q = 0; q < 4; ++q) {
                win[q]     = u0.h2[q];
                win[q + 4] = u1.h2[q];
                win[q + 8] = u2.h2[q];
            }
            win[12] = u3.h2[0]; win[13] = u3.h2[1];
            #pragma unroll
            for (int cc = 0; cc < 4; ++cc) {
                __half2 s = __float2half2_rn(0.0f);
                #pragma unroll
                for (int t = 0; t < 11; ++t)
                    s = __hfma2(wh[t], win[cc + t], s);
                hc[p][cc] = s;
            }
        }

        // SSIM map (fp32), rows 2*rp, 2*rp+1 packed in lo/hi
        const int rp  = 2 * half + rpl;
        const int ylo = oy0 + 2 * rp;
        const bool vlo = ylo < 502, vhi = (ylo + 1) < 502;
        #pragma unroll
        for (int cc = 0; cc < 4; ++cc) {
            if (oc0 + cc < 502) {          // oc0-based: shifted groups masked
                #pragma unroll
                for (int h = 0; h < 2; ++h) {
                    if (h ? vhi : vlo) {
                        const float mu1 = h ? __high2float(hc[0][cc]) : __low2float(hc[0][cc]);
                        const float mu2 = h ? __high2float(hc[1][cc]) : __low2float(hc[1][cc]);
                        const float exx = h ? __high2float(hc[2][cc]) : __low2float(hc[2][cc]);
                        const float eyy = h ? __high2float(hc[3][cc]) : __low2float(hc[3][cc]);
                        const float exy = h ? __high2float(hc[4][cc]) : __low2float(hc[4][cc]);
                        const float m11 = mu1 * mu1, m22 = mu2 * mu2, m12 = mu1 * mu2;
                        const float s1  = exx - m11;
                        const float s2  = eyy - m22;
                        const float s12 = exy - m12;
                        const float num = (2.f * m12 + C1) * (2.f * s12 + C2);
                        const float den = (m11 + m22 + C1) * (s1 + s2 + C2);
                        ssim_acc += num * __builtin_amdgcn_rcpf(den);
                    }
                }
            }
        }
    }

    // -------- block reduction: wave shfl -> LDS -> ONE store per block ------
    float vx = mse_acc, vy = ssim_acc;
    #pragma unroll
    for (int off = 32; off > 0; off >>= 1) {
        vx += __shfl_down(vx, off);
        vy += __shfl_down(vy, off);
    }
    __syncthreads();                     // phase-B LDS reads done; reuse sPh2
    float* redf = reinterpret_cast<float*>(sPh2);
    const int wave = tid >> 6;
    if ((tid & 63) == 0) { redf[wave * 2] = vx; redf[wave * 2 + 1] = vy; }
    __syncthreads();
    if (tid == 0) {
        part[bid] = make_float2(redf[0] + redf[2] + redf[4] + redf[6],
                                redf[1] + redf[3] + redf[5] + redf[7]);
    }
}

__global__ __launch_bounds__(256) void ssim_reduce(
    const float2* __restrict__ part, float* __restrict__ out)
{
    __shared__ float red[8];
    const int tid = threadIdx.x;
    const float4* p4 = reinterpret_cast<const float4*>(part);  // 1536 float4
    float ms = 0.f, ss = 0.f;
    #pragma unroll
    for (int k = 0; k < 6; ++k) {
        const float4 v = p4[tid + k * 256];
        ms += v.x + v.z; ss += v.y + v.w;
    }
    #pragma unroll
    for (int off = 32; off > 0; off >>= 1) {
        ms += __shfl_down(ms, off);
        ss += __shfl_down(ss, off);
    }
    const int wave = tid >> 6;
    if ((tid & 63) == 0) { red[wave * 2] = ms; red[wave * 2 + 1] = ss; }
    __syncthreads();
    if (tid == 0) {
        const float msum = red[0] + red[2] + red[4] + red[6];
        const float ssum = red[1] + red[3] + red[5] + red[7];
        // N_mse = 16*3*512*512 = 12582912 ; N_ssim = 16*3*502*502 = 12096192
        const float mse  = msum * (1.0f / 12582912.0f);
        const float ssim = ssum * (1.0f / 12096192.0f);
        out[0] = 0.16f * mse + 0.84f * (1.0f - ssim);
    }
}

extern "C" void kernel_launch(void* const* d_in, const int* in_sizes, int n_in,
                              void* d_out, int out_size, void* d_ws, size_t ws_size,
                              hipStream_t stream)
{
    const float* pred = (const float*)d_in[0];
    const float* targ = (const float*)d_in[1];
    float2* part = (float2*)d_ws;      // 3072 * 8 B, fully rewritten each launch

    // 48 planes * 64 row-strips = 3072 blocks
    ssim_fused<<<3072, 256, 0, stream>>>(pred, targ, part);
    ssim_reduce<<<1, 256, 0, stream>>>(part, (float*)d_out);
}

// Round 14
// 42.961 us; speedup vs baseline: 1.5367x; 1.0031x over previous
//
#include <hip/hip_runtime.h>
#include <hip/hip_fp16.h>

// Composite loss: 0.16*MSE + 0.84*(1-SSIM), 16x3x512x512 f32, win=11 sigma=1.5
// R14 = R13 with __launch_bounds__(256, 8).
// Evidence: every (256,4) round sat at ~4 blocks/CU even with a 7-block
// LDS/VGPR ceiling (R9 40-44%, R13 32%) -> second arg appears to act as a
// waves/EU cap. VGPR is already 64 (= 8 waves/EU budget) so raising it to 8
// should not spill (canary: WRITE_SIZE) and lifts residency 4 -> 7 blocks.
//   phase A: stream 18 rows, pk-fp16 vertical conv (5 planes x 8 rows)
//   two passes: store 2 row-pairs (20512B LDS), conflict-free horizontal conv
//               + fp32 SSIM map, barrier, repeat for the other 2 row-pairs
//   reduce: per-block partial -> d_ws; 1-block float4 tree reduce.

#define OH 8

struct __align__(8) H2x2 { __half2 a, b; };

__global__ __launch_bounds__(256, 8) void ssim_fused(
    const float* __restrict__ pred, const float* __restrict__ targ,
    float2* __restrict__ part)
{
    __shared__ __half2 sPh2[5 * 2 * 512 + 8];   // 20512 B: [plane][rpl][col]

    // Normalized 11-tap Gaussian (sigma=1.5)
    const float wv[11] = {
        0.00102838f, 0.00759876f, 0.03600078f, 0.10936070f, 0.21300554f,
        0.26601173f,
        0.21300554f, 0.10936070f, 0.03600078f, 0.00759876f, 0.00102838f };
    __half2 wh[11];
    #pragma unroll
    for (int k = 0; k < 11; ++k) wh[k] = __float2half2_rn(wv[k]);

    const int tid = threadIdx.x;
    // XCD-aware bijective swizzle: 3072 blocks = 8 XCDs * 384
    const int bid = ((int)blockIdx.x & 7) * 384 + ((int)blockIdx.x >> 3);
    const int img = bid >> 6;             // 48 planes
    const int oy0 = (bid & 63) * OH;      // 64 row-strips
    const float* __restrict__ P = pred + (size_t)img * (512 * 512);
    const float* __restrict__ T = targ + (size_t)img * (512 * 512);

    // ---------------- phase A: stream 18 rows, pk-fp16 vertical conv --------
    const int c0 = tid * 2;

    __half2 va[5][OH];               // packed col-pair accumulators
    #pragma unroll
    for (int p = 0; p < 5; ++p)
        #pragma unroll
        for (int j = 0; j < OH; ++j) va[p][j] = __float2half2_rn(0.0f);

    float mse_acc = 0.f;

    #pragma unroll
    for (int i = 0; i < OH + 10; ++i) {
        int gy = oy0 + i; if (gy > 511) gy = 511;   // clamped rows feed only masked outputs
        const float2 xv = *reinterpret_cast<const float2*>(P + gy * 512 + c0);
        const float2 yv = *reinterpret_cast<const float2*>(T + gy * 512 + c0);
        const float x0 = __builtin_amdgcn_fmed3f(xv.x, 0.f, 1.f);
        const float x1 = __builtin_amdgcn_fmed3f(xv.y, 0.f, 1.f);
        const float y0 = __builtin_amdgcn_fmed3f(yv.x, 0.f, 1.f);
        const float y1 = __builtin_amdgcn_fmed3f(yv.y, 0.f, 1.f);
        if (i < OH) {   // this block's disjoint MSE rows (fp32)
            const float d0 = x0 - y0, d1 = x1 - y1;
            mse_acc = fmaf(d0, d0, mse_acc);
            mse_acc = fmaf(d1, d1, mse_acc);
        }
        const __half2 hx = __float22half2_rn(make_float2(x0, x1));
        const __half2 hy = __float22half2_rn(make_float2(y0, y1));
        const __half2 pr[5] = { hx, hy, __hmul2(hx, hx), __hmul2(hy, hy),
                                __hmul2(hx, hy) };
        #pragma unroll
        for (int j = 0; j < OH; ++j) {
            const int k = i - j;
            if (k >= 0 && k <= 10) {
                #pragma unroll
                for (int p = 0; p < 5; ++p)
                    va[p][j] = __hfma2(wh[k], pr[p], va[p][j]);
            }
        }
    }

    // ------------- two passes: store 2 row-pairs, conv+map them -------------
    float ssim_acc = 0.f;
    const float C1 = 0.0001f, C2 = 0.0009f;

    const int rpl = tid >> 7;           // local row-pair 0..1
    const int oc0 = (tid & 127) * 4;    // output cols oc0..oc0+3
    // groups with oc0>=504 are fully masked; clamp their reads in-row
    const int rc0 = (oc0 >= 504) ? 496 : oc0;

    #pragma unroll
    for (int half = 0; half < 2; ++half) {
        if (half) __syncthreads();      // pass-0 reads done before overwrite

        // store row-pairs jp = 2*half+jpl as ONE 8B write each
        #pragma unroll
        for (int p = 0; p < 5; ++p)
            #pragma unroll
            for (int jpl = 0; jpl < 2; ++jpl) {
                const int jp = 2 * half + jpl;
                const __half2 a = va[p][2 * jp], b = va[p][2 * jp + 1];
                H2x2 st;
                st.a = __halves2half2(__low2half(a),  __low2half(b));
                st.b = __halves2half2(__high2half(a), __high2half(b));
                *reinterpret_cast<H2x2*>(&sPh2[(p * 2 + jpl) * 512 + c0]) = st;
            }

        __syncthreads();

        // conflict-free horizontal conv: lane reads contiguous 16B chunks
        __half2 hc[5][4];
        union U4 { float4 f4; __half2 h2[4]; };
        union U2 { float2 f2; __half2 h2[2]; };
        #pragma unroll
        for (int p = 0; p < 5; ++p) {
            const __half2* base = &sPh2[(p * 2 + rpl) * 512 + rc0];
            __half2 win[14];
            U4 u0, u1, u2; U2 u3;
            u0.f4 = *reinterpret_cast<const float4*>(base);
            u1.f4 = *reinterpret_cast<const float4*>(base + 4);
            u2.f4 = *reinterpret_cast<const float4*>(base + 8);
            u3.f2 = *reinterpret_cast<const float2*>(base + 12);
            #pragma unroll
            for (int q = 0; q < 4; ++q) {
                win[q]     = u0.h2[q];
                win[q + 4] = u1.h2[q];
                win[q + 8] = u2.h2[q];
            }
            win[12] = u3.h2[0]; win[13] = u3.h2[1];
            #pragma unroll
            for (int cc = 0; cc < 4; ++cc) {
                __half2 s = __float2half2_rn(0.0f);
                #pragma unroll
                for (int t = 0; t < 11; ++t)
                    s = __hfma2(wh[t], win[cc + t], s);
                hc[p][cc] = s;
            }
        }

        // SSIM map (fp32), rows 2*rp, 2*rp+1 packed in lo/hi
        const int rp  = 2 * half + rpl;
        const int ylo = oy0 + 2 * rp;
        const bool vlo = ylo < 502, vhi = (ylo + 1) < 502;
        #pragma unroll
        for (int cc = 0; cc < 4; ++cc) {
            if (oc0 + cc < 502) {          // oc0-based: shifted groups masked
                #pragma unroll
                for (int h = 0; h < 2; ++h) {
                    if (h ? vhi : vlo) {
                        const float mu1 = h ? __high2float(hc[0][cc]) : __low2float(hc[0][cc]);
                        const float mu2 = h ? __high2float(hc[1][cc]) : __low2float(hc[1][cc]);
                        const float exx = h ? __high2float(hc[2][cc]) : __low2float(hc[2][cc]);
                        const float eyy = h ? __high2float(hc[3][cc]) : __low2float(hc[3][cc]);
                        const float exy = h ? __high2float(hc[4][cc]) : __low2float(hc[4][cc]);
                        const float m11 = mu1 * mu1, m22 = mu2 * mu2, m12 = mu1 * mu2;
                        const float s1  = exx - m11;
                        const float s2  = eyy - m22;
                        const float s12 = exy - m12;
                        const float num = (2.f * m12 + C1) * (2.f * s12 + C2);
                        const float den = (m11 + m22 + C1) * (s1 + s2 + C2);
                        ssim_acc += num * __builtin_amdgcn_rcpf(den);
                    }
                }
            }
        }
    }

    // -------- block reduction: wave shfl -> LDS -> ONE store per block ------
    float vx = mse_acc, vy = ssim_acc;
    #pragma unroll
    for (int off = 32; off > 0; off >>= 1) {
        vx += __shfl_down(vx, off);
        vy += __shfl_down(vy, off);
    }
    __syncthreads();                     // phase-B LDS reads done; reuse sPh2
    float* redf = reinterpret_cast<float*>(sPh2);
    const int wave = tid >> 6;
    if ((tid & 63) == 0) { redf[wave * 2] = vx; redf[wave * 2 + 1] = vy; }
    __syncthreads();
    if (tid == 0) {
        part[bid] = make_float2(redf[0] + redf[2] + redf[4] + redf[6],
                                redf[1] + redf[3] + redf[5] + redf[7]);
    }
}

__global__ __launch_bounds__(256) void ssim_reduce(
    const float2* __restrict__ part, float* __restrict__ out)
{
    __shared__ float red[8];
    const int tid = threadIdx.x;
    const float4* p4 = reinterpret_cast<const float4*>(part);  // 1536 float4
    float ms = 0.f, ss = 0.f;
    #pragma unroll
    for (int k = 0; k < 6; ++k) {
        const float4 v = p4[tid + k * 256];
        ms += v.x + v.z; ss += v.y + v.w;
    }
    #pragma unroll
    for (int off = 32; off > 0; off >>= 1) {
        ms += __shfl_down(ms, off);
        ss += __shfl_down(ss, off);
    }
    const int wave = tid >> 6;
    if ((tid & 63) == 0) { red[wave * 2] = ms; red[wave * 2 + 1] = ss; }
    __syncthreads();
    if (tid == 0) {
        const float msum = red[0] + red[2] + red[4] + red[6];
        const float ssum = red[1] + red[3] + red[5] + red[7];
        // N_mse = 16*3*512*512 = 12582912 ; N_ssim = 16*3*502*502 = 12096192
        const float mse  = msum * (1.0f / 12582912.0f);
        const float ssim = ssum * (1.0f / 12096192.0f);
        out[0] = 0.16f * mse + 0.84f * (1.0f - ssim);
    }
}

extern "C" void kernel_launch(void* const* d_in, const int* in_sizes, int n_in,
                              void* d_out, int out_size, void* d_ws, size_t ws_size,
                              hipStream_t stream)
{
    const float* pred = (const float*)d_in[0];
    const float* targ = (const float*)d_in[1];
    float2* part = (float2*)d_ws;      // 3072 * 8 B, fully rewritten each launch

    // 48 planes * 64 row-strips = 3072 blocks
    ssim_fused<<<3072, 256, 0, stream>>>(pred, targ, part);
    ssim_reduce<<<1, 256, 0, stream>>>(part, (float*)d_out);
}

// Round 15
// 41.364 us; speedup vs baseline: 1.5960x; 1.0386x over previous
//
#include <hip/hip_runtime.h>
#include <hip/hip_fp16.h>

// Composite loss: 0.16*MSE + 0.84*(1-SSIM), 16x3x512x512 f32, win=11 sigma=1.5
// R15 = R13 + FORCED batch-issue of all 36 phase-A loads via inline asm.
// R4/R5's plain-load batching silently failed (VGPR stayed 52 -- IR-level
// sinking); volatile asm loads cannot be sunk/folded, so 72 VGPRs of load
// destinations stay in flight -> one ~700cy stall/wave instead of ~7.
//   phase A: 36 asm global_load_dwordx2 -> vmcnt(0) -> sched_barrier ->
//            pk-fp16 vertical conv (5 planes x 8 rows)
//   two passes: store 2 row-pairs (20512B LDS), conflict-free horizontal conv
//               + fp32 SSIM map, barrier, repeat
//   reduce: per-block partial -> d_ws; 1-block float4 tree reduce.

#define OH 8

struct __align__(8) H2x2 { __half2 a, b; };

__global__ __launch_bounds__(256, 3) void ssim_fused(
    const float* __restrict__ pred, const float* __restrict__ targ,
    float2* __restrict__ part)
{
    __shared__ __half2 sPh2[5 * 2 * 512 + 8];   // 20512 B: [plane][rpl][col]

    // Normalized 11-tap Gaussian (sigma=1.5)
    const float wv[11] = {
        0.00102838f, 0.00759876f, 0.03600078f, 0.10936070f, 0.21300554f,
        0.26601173f,
        0.21300554f, 0.10936070f, 0.03600078f, 0.00759876f, 0.00102838f };
    __half2 wh[11];
    #pragma unroll
    for (int k = 0; k < 11; ++k) wh[k] = __float2half2_rn(wv[k]);

    const int tid = threadIdx.x;
    // XCD-aware bijective swizzle: 3072 blocks = 8 XCDs * 384
    const int bid = ((int)blockIdx.x & 7) * 384 + ((int)blockIdx.x >> 3);
    const int img = bid >> 6;             // 48 planes
    const int oy0 = (bid & 63) * OH;      // 64 row-strips
    const float* __restrict__ P = pred + (size_t)img * (512 * 512);
    const float* __restrict__ T = targ + (size_t)img * (512 * 512);

    // ------- phase A load: ALL 36 loads issued before any wait --------------
    const int c0 = tid * 2;

    float2 xr[OH + 10], yr[OH + 10];
    #pragma unroll
    for (int i = 0; i < OH + 10; ++i) {
        int gy = oy0 + i; if (gy > 511) gy = 511;   // clamped rows feed only masked outputs
        asm volatile("global_load_dwordx2 %0, %1, off"
                     : "=v"(xr[i]) : "v"(P + gy * 512 + c0));
        asm volatile("global_load_dwordx2 %0, %1, off"
                     : "=v"(yr[i]) : "v"(T + gy * 512 + c0));
    }
    asm volatile("s_waitcnt vmcnt(0)" ::: "memory");
    __builtin_amdgcn_sched_barrier(0);   // rule #18: no consumer hoists past wait

    // ---------------- phase A: pk-fp16 vertical conv ------------------------
    __half2 va[5][OH];               // packed col-pair accumulators
    #pragma unroll
    for (int p = 0; p < 5; ++p)
        #pragma unroll
        for (int j = 0; j < OH; ++j) va[p][j] = __float2half2_rn(0.0f);

    float mse_acc = 0.f;

    #pragma unroll
    for (int i = 0; i < OH + 10; ++i) {
        const float x0 = __builtin_amdgcn_fmed3f(xr[i].x, 0.f, 1.f);
        const float x1 = __builtin_amdgcn_fmed3f(xr[i].y, 0.f, 1.f);
        const float y0 = __builtin_amdgcn_fmed3f(yr[i].x, 0.f, 1.f);
        const float y1 = __builtin_amdgcn_fmed3f(yr[i].y, 0.f, 1.f);
        if (i < OH) {   // this block's disjoint MSE rows (fp32)
            const float d0 = x0 - y0, d1 = x1 - y1;
            mse_acc = fmaf(d0, d0, mse_acc);
            mse_acc = fmaf(d1, d1, mse_acc);
        }
        const __half2 hx = __float22half2_rn(make_float2(x0, x1));
        const __half2 hy = __float22half2_rn(make_float2(y0, y1));
        const __half2 pr[5] = { hx, hy, __hmul2(hx, hx), __hmul2(hy, hy),
                                __hmul2(hx, hy) };
        #pragma unroll
        for (int j = 0; j < OH; ++j) {
            const int k = i - j;
            if (k >= 0 && k <= 10) {
                #pragma unroll
                for (int p = 0; p < 5; ++p)
                    va[p][j] = __hfma2(wh[k], pr[p], va[p][j]);
            }
        }
    }

    // ------------- two passes: store 2 row-pairs, conv+map them -------------
    float ssim_acc = 0.f;
    const float C1 = 0.0001f, C2 = 0.0009f;

    const int rpl = tid >> 7;           // local row-pair 0..1
    const int oc0 = (tid & 127) * 4;    // output cols oc0..oc0+3
    // groups with oc0>=504 are fully masked; clamp their reads in-row
    const int rc0 = (oc0 >= 504) ? 496 : oc0;

    #pragma unroll
    for (int half = 0; half < 2; ++half) {
        if (half) __syncthreads();      // pass-0 reads done before overwrite

        // store row-pairs jp = 2*half+jpl as ONE 8B write each
        #pragma unroll
        for (int p = 0; p < 5; ++p)
            #pragma unroll
            for (int jpl = 0; jpl < 2; ++jpl) {
                const int jp = 2 * half + jpl;
                const __half2 a = va[p][2 * jp], b = va[p][2 * jp + 1];
                H2x2 st;
                st.a = __halves2half2(__low2half(a),  __low2half(b));
                st.b = __halves2half2(__high2half(a), __high2half(b));
                *reinterpret_cast<H2x2*>(&sPh2[(p * 2 + jpl) * 512 + c0]) = st;
            }

        __syncthreads();

        // conflict-free horizontal conv: lane reads contiguous 16B chunks
        __half2 hc[5][4];
        union U4 { float4 f4; __half2 h2[4]; };
        union U2 { float2 f2; __half2 h2[2]; };
        #pragma unroll
        for (int p = 0; p < 5; ++p) {
            const __half2* base = &sPh2[(p * 2 + rpl) * 512 + rc0];
            __half2 win[14];
            U4 u0, u1, u2; U2 u3;
            u0.f4 = *reinterpret_cast<const float4*>(base);
            u1.f4 = *reinterpret_cast<const float4*>(base + 4);
            u2.f4 = *reinterpret_cast<const float4*>(base + 8);
            u3.f2 = *reinterpret_cast<const float2*>(base + 12);
            #pragma unroll
            for (int q = 0; q < 4; ++q) {
                win[q]     = u0.h2[q];
                win[q + 4] = u1.h2[q];
                win[q + 8] = u2.h2[q];
            }
            win[12] = u3.h2[0]; win[13] = u3.h2[1];
            #pragma unroll
            for (int cc = 0; cc < 4; ++cc) {
                __half2 s = __float2half2_rn(0.0f);
                #pragma unroll
                for (int t = 0; t < 11; ++t)
                    s = __hfma2(wh[t], win[cc + t], s);
                hc[p][cc] = s;
            }
        }

        // SSIM map (fp32), rows 2*rp, 2*rp+1 packed in lo/hi
        const int rp  = 2 * half + rpl;
        const int ylo = oy0 + 2 * rp;
        const bool vlo = ylo < 502, vhi = (ylo + 1) < 502;
        #pragma unroll
        for (int cc = 0; cc < 4; ++cc) {
            if (oc0 + cc < 502) {          // oc0-based: shifted groups masked
                #pragma unroll
                for (int h = 0; h < 2; ++h) {
                    if (h ? vhi : vlo) {
                        const float mu1 = h ? __high2float(hc[0][cc]) : __low2float(hc[0][cc]);
                        const float mu2 = h ? __high2float(hc[1][cc]) : __low2float(hc[1][cc]);
                        const float exx = h ? __high2float(hc[2][cc]) : __low2float(hc[2][cc]);
                        const float eyy = h ? __high2float(hc[3][cc]) : __low2float(hc[3][cc]);
                        const float exy = h ? __high2float(hc[4][cc]) : __low2float(hc[4][cc]);
                        const float m11 = mu1 * mu1, m22 = mu2 * mu2, m12 = mu1 * mu2;
                        const float s1  = exx - m11;
                        const float s2  = eyy - m22;
                        const float s12 = exy - m12;
                        const float num = (2.f * m12 + C1) * (2.f * s12 + C2);
                        const float den = (m11 + m22 + C1) * (s1 + s2 + C2);
                        ssim_acc += num * __builtin_amdgcn_rcpf(den);
                    }
                }
            }
        }
    }

    // -------- block reduction: wave shfl -> LDS -> ONE store per block ------
    float vx = mse_acc, vy = ssim_acc;
    #pragma unroll
    for (int off = 32; off > 0; off >>= 1) {
        vx += __shfl_down(vx, off);
        vy += __shfl_down(vy, off);
    }
    __syncthreads();                     // phase-B LDS reads done; reuse sPh2
    float* redf = reinterpret_cast<float*>(sPh2);
    const int wave = tid >> 6;
    if ((tid & 63) == 0) { redf[wave * 2] = vx; redf[wave * 2 + 1] = vy; }
    __syncthreads();
    if (tid == 0) {
        part[bid] = make_float2(redf[0] + redf[2] + redf[4] + redf[6],
                                redf[1] + redf[3] + redf[5] + redf[7]);
    }
}

__global__ __launch_bounds__(256) void ssim_reduce(
    const float2* __restrict__ part, float* __restrict__ out)
{
    __shared__ float red[8];
    const int tid = threadIdx.x;
    const float4* p4 = reinterpret_cast<const float4*>(part);  // 1536 float4
    float ms = 0.f, ss = 0.f;
    #pragma unroll
    for (int k = 0; k < 6; ++k) {
        const float4 v = p4[tid + k * 256];
        ms += v.x + v.z; ss += v.y + v.w;
    }
    #pragma unroll
    for (int off = 32; off > 0; off >>= 1) {
        ms += __shfl_down(ms, off);
        ss += __shfl_down(ss, off);
    }
    const int wave = tid >> 6;
    if ((tid & 63) == 0) { red[wave * 2] = ms; red[wave * 2 + 1] = ss; }
    __syncthreads();
    if (tid == 0) {
        const float msum = red[0] + red[2] + red[4] + red[6];
        const float ssum = red[1] + red[3] + red[5] + red[7];
        // N_mse = 16*3*512*512 = 12582912 ; N_ssim = 16*3*502*502 = 12096192
        const float mse  = msum * (1.0f / 12582912.0f);
        const float ssim = ssum * (1.0f / 12096192.0f);
        out[0] = 0.16f * mse + 0.84f * (1.0f - ssim);
    }
}

extern "C" void kernel_launch(void* const* d_in, const int* in_sizes, int n_in,
                              void* d_out, int out_size, void* d_ws, size_t ws_size,
                              hipStream_t stream)
{
    const float* pred = (const float*)d_in[0];
    const float* targ = (const float*)d_in[1];
    float2* part = (float2*)d_ws;      // 3072 * 8 B, fully rewritten each launch

    // 48 planes * 64 row-strips = 3072 blocks
    ssim_fused<<<3072, 256, 0, stream>>>(pred, targ, part);
    ssim_reduce<<<1, 256, 0, stream>>>(part, (float*)d_out);
}